// Round 1
// baseline (120.225 us; speedup 1.0000x reference)
//
#include <hip/hip_runtime.h>
#include <math.h>

#define B_SZ 1024
#define D_SZ 2048
#define MARGIN 0.3f

#define BM 64
#define BN 64
#define BK 32

// ws layout (bytes):
// [0,     4096)  sq   (1024 f32)
// [4096,  8192)  hp   (1024 int bits of hardest-pos, init 0 = 0.0f)
// [8192, 12288)  hn   (1024 int bits of hardest-neg, init +inf)
// [12288,16384)  flags(1024 int: bit0 = any pos, bit1 = any neg)

__global__ __launch_bounds__(256) void sq_kernel(const float* __restrict__ F,
                                                 float* __restrict__ sq) {
    int row = blockIdx.x;
    const float4* r4 = (const float4*)(F + (size_t)row * D_SZ);
    int t = threadIdx.x;
    float s = 0.f;
#pragma unroll
    for (int q = 0; q < 2; ++q) {
        float4 v = r4[t + q * 256];
        s += v.x * v.x + v.y * v.y + v.z * v.z + v.w * v.w;
    }
    for (int off = 32; off; off >>= 1) s += __shfl_down(s, off);
    __shared__ float wsum[4];
    if ((t & 63) == 0) wsum[t >> 6] = s;
    __syncthreads();
    if (t == 0) sq[row] = wsum[0] + wsum[1] + wsum[2] + wsum[3];
}

__global__ __launch_bounds__(256) void init_kernel(int* __restrict__ hp,
                                                   int* __restrict__ hn,
                                                   int* __restrict__ flags) {
    int i = blockIdx.x * 256 + threadIdx.x;
    hp[i] = 0;            // 0.0f as bits; real dists are > 0
    hn[i] = 0x7F800000;   // +inf
    flags[i] = 0;
}

__global__ __launch_bounds__(256) void dist_kernel(
    const float* __restrict__ F, const int* __restrict__ labels,
    const float* __restrict__ sq, int* __restrict__ hp, int* __restrict__ hn,
    int* __restrict__ flags) {
    __shared__ float As[BK][BM];
    __shared__ float Bs[BK][BN];
    __shared__ int labR[BM], labC[BN];
    __shared__ float sqR[BM], sqC[BN];

    const int rowBase = blockIdx.y * BM;
    const int colBase = blockIdx.x * BN;
    const int t = threadIdx.x;
    const int tx = t & 15;       // col group
    const int ty = t >> 4;       // row group

    if (t < 64) {
        labR[t] = labels[rowBase + t];
        sqR[t] = sq[rowBase + t];
    } else if (t < 128) {
        int u = t - 64;
        labC[u] = labels[colBase + u];
        sqC[u] = sq[colBase + u];
    }

    float acc[4][4] = {{0.f}};

    const int m = t & 63;        // which row of the tile this thread stages
    const int q = t >> 6;        // which 8-float chunk of K
    const float* aRow = F + (size_t)(rowBase + m) * D_SZ + q * 8;
    const float* bRow = F + (size_t)(colBase + m) * D_SZ + q * 8;

    for (int k0 = 0; k0 < D_SZ; k0 += BK) {
        float4 a0 = *(const float4*)(aRow + k0);
        float4 a1 = *(const float4*)(aRow + k0 + 4);
        float4 b0 = *(const float4*)(bRow + k0);
        float4 b1 = *(const float4*)(bRow + k0 + 4);
        __syncthreads();
        int kb = q * 8;
        As[kb + 0][m] = a0.x; As[kb + 1][m] = a0.y;
        As[kb + 2][m] = a0.z; As[kb + 3][m] = a0.w;
        As[kb + 4][m] = a1.x; As[kb + 5][m] = a1.y;
        As[kb + 6][m] = a1.z; As[kb + 7][m] = a1.w;
        Bs[kb + 0][m] = b0.x; Bs[kb + 1][m] = b0.y;
        Bs[kb + 2][m] = b0.z; Bs[kb + 3][m] = b0.w;
        Bs[kb + 4][m] = b1.x; Bs[kb + 5][m] = b1.y;
        Bs[kb + 6][m] = b1.z; Bs[kb + 7][m] = b1.w;
        __syncthreads();
#pragma unroll
        for (int kk = 0; kk < BK; ++kk) {
            float4 a = *(const float4*)&As[kk][ty * 4];
            float4 b = *(const float4*)&Bs[kk][tx * 4];
            acc[0][0] += a.x * b.x; acc[0][1] += a.x * b.y;
            acc[0][2] += a.x * b.z; acc[0][3] += a.x * b.w;
            acc[1][0] += a.y * b.x; acc[1][1] += a.y * b.y;
            acc[1][2] += a.y * b.z; acc[1][3] += a.y * b.w;
            acc[2][0] += a.z * b.x; acc[2][1] += a.z * b.y;
            acc[2][2] += a.z * b.z; acc[2][3] += a.z * b.w;
            acc[3][0] += a.w * b.x; acc[3][1] += a.w * b.y;
            acc[3][2] += a.w * b.z; acc[3][3] += a.w * b.w;
        }
    }

    // Epilogue: dist + masked max/min per row of the tile.
    float mp[4], mn[4];
    int pf[4];
#pragma unroll
    for (int r = 0; r < 4; ++r) {
        const int i = rowBase + ty * 4 + r;
        const int li = labR[ty * 4 + r];
        const float si = sqR[ty * 4 + r];
        mp[r] = -3.4e38f;
        mn[r] = 3.4e38f;
        pf[r] = 0;
#pragma unroll
        for (int c = 0; c < 4; ++c) {
            const int j = colBase + tx * 4 + c;
            const float d2 = si + sqC[tx * 4 + c] - 2.f * acc[r][c];
            const float dist = sqrtf(fmaxf(d2, 1e-12f));
            const bool eq = (li == labC[tx * 4 + c]);
            if (eq && (i != j)) {
                mp[r] = fmaxf(mp[r], dist);
                pf[r] |= 1;
            }
            if (!eq) {
                mn[r] = fminf(mn[r], dist);
                pf[r] |= 2;
            }
        }
    }
    // Reduce across the 16 tx lanes (lane bits 0..3).
#pragma unroll
    for (int mask = 1; mask < 16; mask <<= 1) {
#pragma unroll
        for (int r = 0; r < 4; ++r) {
            mp[r] = fmaxf(mp[r], __shfl_xor(mp[r], mask));
            mn[r] = fminf(mn[r], __shfl_xor(mn[r], mask));
            pf[r] |= __shfl_xor(pf[r], mask);
        }
    }
    if (tx == 0) {
#pragma unroll
        for (int r = 0; r < 4; ++r) {
            const int i = rowBase + ty * 4 + r;
            if (pf[r] & 1) atomicMax(&hp[i], __float_as_int(mp[r]));
            if (pf[r] & 2) atomicMin(&hn[i], __float_as_int(mn[r]));
            if (pf[r]) atomicOr(&flags[i], pf[r]);
        }
    }
}

__global__ __launch_bounds__(1024) void final_kernel(const int* __restrict__ hp,
                                                     const int* __restrict__ hn,
                                                     const int* __restrict__ flags,
                                                     float* __restrict__ out) {
    __shared__ float ssum[16];
    __shared__ int svalid[16], sact[16];
    const int t = threadIdx.x;
    const float hpv = __int_as_float(hp[t]);
    const float hnv = __int_as_float(hn[t]);
    const int f = flags[t];
    const bool valid = (f == 3);
    float pr = fmaxf(hpv - hnv + MARGIN, 0.f);
    if (!valid) pr = 0.f;
    int act = (valid && pr > 0.f) ? 1 : 0;
    int vld = valid ? 1 : 0;
    float s = pr;
    for (int off = 32; off; off >>= 1) {
        s += __shfl_down(s, off);
        act += __shfl_down(act, off);
        vld += __shfl_down(vld, off);
    }
    if ((t & 63) == 0) {
        ssum[t >> 6] = s;
        svalid[t >> 6] = vld;
        sact[t >> 6] = act;
    }
    __syncthreads();
    if (t == 0) {
        float tot = 0.f;
        int nv = 0, na = 0;
#pragma unroll
        for (int i = 0; i < 16; ++i) {
            tot += ssum[i];
            nv += svalid[i];
            na += sact[i];
        }
        out[0] = tot / (float)(nv > 1 ? nv : 1);
        out[1] = (float)na;
    }
}

extern "C" void kernel_launch(void* const* d_in, const int* in_sizes, int n_in,
                              void* d_out, int out_size, void* d_ws, size_t ws_size,
                              hipStream_t stream) {
    const float* F = (const float*)d_in[0];
    const int* labels = (const int*)d_in[1];
    float* out = (float*)d_out;

    char* ws = (char*)d_ws;
    float* sq = (float*)(ws);
    int* hp = (int*)(ws + 4096);
    int* hn = (int*)(ws + 8192);
    int* flags = (int*)(ws + 12288);

    sq_kernel<<<B_SZ, 256, 0, stream>>>(F, sq);
    init_kernel<<<B_SZ / 256, 256, 0, stream>>>(hp, hn, flags);
    dim3 grid(B_SZ / BN, B_SZ / BM);
    dist_kernel<<<grid, 256, 0, stream>>>(F, labels, sq, hp, hn, flags);
    final_kernel<<<1, 1024, 0, stream>>>(hp, hn, flags, out);
}

// Round 2
// 52.870 us; speedup vs baseline: 2.2740x; 2.2740x over previous
//
#include <hip/hip_runtime.h>
#include <math.h>

#define B_SZ 1024
#define D_SZ 2048
#define MARGIN 0.3f

typedef short bf16x8 __attribute__((ext_vector_type(8)));
typedef float f32x4 __attribute__((ext_vector_type(4)));

union FragU { uint4 u; bf16x8 v; };
union Pack8 { unsigned short s[8]; uint4 u; };

__device__ __forceinline__ unsigned short f2bf(float x) {
    unsigned int u = __float_as_uint(x);
    unsigned int r = (u + 0x7FFFu + ((u >> 16) & 1u)) >> 16;
    return (unsigned short)r;
}
__device__ __forceinline__ float bf2f(unsigned short h) {
    return __uint_as_float(((unsigned int)h) << 16);
}

// ---------------- shared small kernels ----------------

__global__ __launch_bounds__(256) void sq_kernel(const float* __restrict__ F,
                                                 float* __restrict__ sq) {
    int row = blockIdx.x;
    const float4* r4 = (const float4*)(F + (size_t)row * D_SZ);
    int t = threadIdx.x;
    float s = 0.f;
#pragma unroll
    for (int q = 0; q < 2; ++q) {
        float4 v = r4[t + q * 256];
        s += v.x * v.x + v.y * v.y + v.z * v.z + v.w * v.w;
    }
    for (int off = 32; off; off >>= 1) s += __shfl_down(s, off);
    __shared__ float wsum[4];
    if ((t & 63) == 0) wsum[t >> 6] = s;
    __syncthreads();
    if (t == 0) sq[row] = wsum[0] + wsum[1] + wsum[2] + wsum[3];
}

__global__ __launch_bounds__(256) void init_kernel(int* __restrict__ hp,
                                                   int* __restrict__ hn,
                                                   int* __restrict__ flags) {
    int i = blockIdx.x * 256 + threadIdx.x;
    hp[i] = 0;            // 0.0f bits; real dists are > 0
    hn[i] = 0x7F800000;   // +inf
    flags[i] = 0;
}

__global__ __launch_bounds__(1024) void final_kernel(const int* __restrict__ hp,
                                                     const int* __restrict__ hn,
                                                     const int* __restrict__ flags,
                                                     float* __restrict__ out) {
    __shared__ float ssum[16];
    __shared__ int svalid[16], sact[16];
    const int t = threadIdx.x;
    const float hpv = __int_as_float(hp[t]);
    const float hnv = __int_as_float(hn[t]);
    const int f = flags[t];
    const bool valid = (f == 3);
    float pr = fmaxf(hpv - hnv + MARGIN, 0.f);
    if (!valid) pr = 0.f;
    int act = (valid && pr > 0.f) ? 1 : 0;
    int vld = valid ? 1 : 0;
    float s = pr;
    for (int off = 32; off; off >>= 1) {
        s += __shfl_down(s, off);
        act += __shfl_down(act, off);
        vld += __shfl_down(vld, off);
    }
    if ((t & 63) == 0) {
        ssum[t >> 6] = s;
        svalid[t >> 6] = vld;
        sact[t >> 6] = act;
    }
    __syncthreads();
    if (t == 0) {
        float tot = 0.f;
        int nv = 0, na = 0;
#pragma unroll
        for (int i = 0; i < 16; ++i) {
            tot += ssum[i];
            nv += svalid[i];
            na += sact[i];
        }
        out[0] = tot / (float)(nv > 1 ? nv : 1);
        out[1] = (float)na;
    }
}

// ---------------- fast path: bf16 hi/lo MFMA ----------------

__global__ __launch_bounds__(256) void prep_kernel(const float* __restrict__ F,
                                                   unsigned short* __restrict__ hi,
                                                   unsigned short* __restrict__ lo) {
    const int idx = (blockIdx.x * 256 + threadIdx.x) * 8;
    float4 a = *(const float4*)(F + idx);
    float4 b = *(const float4*)(F + idx + 4);
    float x[8] = {a.x, a.y, a.z, a.w, b.x, b.y, b.z, b.w};
    Pack8 h, l;
#pragma unroll
    for (int e = 0; e < 8; ++e) {
        h.s[e] = f2bf(x[e]);
        l.s[e] = f2bf(x[e] - bf2f(h.s[e]));
    }
    *(uint4*)(hi + idx) = h.u;
    *(uint4*)(lo + idx) = l.u;
}

// LDS tile: [64 rows][72 shorts] (64 data + 8 pad) per operand piece.
#define ROWP 72
#define TILE_SH (64 * ROWP)       // 4608 shorts per tile piece
#define BUF_SH (4 * TILE_SH)      // Ahi, Alo, Bhi, Blo

__device__ __forceinline__ void load8(uint4* r,
                                      const unsigned short* __restrict__ Fhi,
                                      const unsigned short* __restrict__ Flo,
                                      int rowBase, int colBase, int k0, int t) {
#pragma unroll
    for (int q = 0; q < 2; ++q) {
        const int s = q * 256 + t;
        const int m = s >> 3;
        const int c = s & 7;
        const size_t offA = (size_t)(rowBase + m) * D_SZ + k0 + c * 8;
        const size_t offB = (size_t)(colBase + m) * D_SZ + k0 + c * 8;
        r[q * 4 + 0] = *(const uint4*)(Fhi + offA);
        r[q * 4 + 1] = *(const uint4*)(Flo + offA);
        r[q * 4 + 2] = *(const uint4*)(Fhi + offB);
        r[q * 4 + 3] = *(const uint4*)(Flo + offB);
    }
}

__device__ __forceinline__ void write8(const uint4* r, unsigned short* __restrict__ buf,
                                       int t) {
#pragma unroll
    for (int q = 0; q < 2; ++q) {
        const int s = q * 256 + t;
        const int m = s >> 3;
        const int c = s & 7;
        const int off = m * ROWP + c * 8;
        *(uint4*)(buf + off) = r[q * 4 + 0];
        *(uint4*)(buf + TILE_SH + off) = r[q * 4 + 1];
        *(uint4*)(buf + 2 * TILE_SH + off) = r[q * 4 + 2];
        *(uint4*)(buf + 3 * TILE_SH + off) = r[q * 4 + 3];
    }
}

__global__ __launch_bounds__(256) void dist_mfma_kernel(
    const unsigned short* __restrict__ Fhi, const unsigned short* __restrict__ Flo,
    const int* __restrict__ labels, const float* __restrict__ sq,
    int* __restrict__ hp, int* __restrict__ hn, int* __restrict__ flags) {
    __shared__ __align__(16) unsigned short smem[2 * BUF_SH];
    __shared__ int labR[64], labC[64];
    __shared__ float sqR[64], sqC[64];

    // unrank upper-triangle tile index
    int b = blockIdx.x;
    int bi = 0;
    while (b >= 16 - bi) { b -= 16 - bi; ++bi; }
    const int bj = bi + b;
    const int rowBase = bi * 64;
    const int colBase = bj * 64;
    const int t = threadIdx.x;

    if (t < 64) {
        labR[t] = labels[rowBase + t];
        sqR[t] = sq[rowBase + t];
    } else if (t < 128) {
        int u = t - 64;
        labC[u] = labels[colBase + u];
        sqC[u] = sq[colBase + u];
    }

    const int lane = t & 63;
    const int w = t >> 6;
    const int wr = w >> 1;
    const int wc = w & 1;

    uint4 r[8];
    load8(r, Fhi, Flo, rowBase, colBase, 0, t);
    write8(r, smem, t);
    __syncthreads();

    f32x4 acc[2][2];
#pragma unroll
    for (int a = 0; a < 2; ++a)
#pragma unroll
        for (int c = 0; c < 2; ++c) acc[a][c] = (f32x4){0.f, 0.f, 0.f, 0.f};

    for (int step = 0; step < 32; ++step) {
        const int cur = step & 1;
        if (step + 1 < 32) load8(r, Fhi, Flo, rowBase, colBase, (step + 1) * 64, t);

        const unsigned short* base = smem + cur * BUF_SH;
#pragma unroll
        for (int kb = 0; kb < 64; kb += 32) {
            FragU ahi[2], alo[2], bhi[2], blo[2];
#pragma unroll
            for (int fr = 0; fr < 2; ++fr) {
                const int rowA = wr * 32 + fr * 16 + (lane & 15);
                const int offA = rowA * ROWP + kb + ((lane >> 4) * 8);
                ahi[fr].u = *(const uint4*)(base + offA);
                alo[fr].u = *(const uint4*)(base + TILE_SH + offA);
                const int rowB = wc * 32 + fr * 16 + (lane & 15);
                const int offB = rowB * ROWP + kb + ((lane >> 4) * 8);
                bhi[fr].u = *(const uint4*)(base + 2 * TILE_SH + offB);
                blo[fr].u = *(const uint4*)(base + 3 * TILE_SH + offB);
            }
#pragma unroll
            for (int fr = 0; fr < 2; ++fr)
#pragma unroll
                for (int fc = 0; fc < 2; ++fc) {
                    acc[fr][fc] = __builtin_amdgcn_mfma_f32_16x16x32_bf16(
                        ahi[fr].v, bhi[fc].v, acc[fr][fc], 0, 0, 0);
                    acc[fr][fc] = __builtin_amdgcn_mfma_f32_16x16x32_bf16(
                        ahi[fr].v, blo[fc].v, acc[fr][fc], 0, 0, 0);
                    acc[fr][fc] = __builtin_amdgcn_mfma_f32_16x16x32_bf16(
                        alo[fr].v, bhi[fc].v, acc[fr][fc], 0, 0, 0);
                }
        }

        if (step + 1 < 32) write8(r, smem + (cur ^ 1) * BUF_SH, t);
        __syncthreads();
    }

    // Epilogue: dist + row-side and col-side masked max/min.
    const float BIG = 1e38f;
    float mpr[2][4], mnr[2][4], mpc[2], mnc[2];
#pragma unroll
    for (int fr = 0; fr < 2; ++fr)
#pragma unroll
        for (int rg = 0; rg < 4; ++rg) {
            mpr[fr][rg] = -BIG;
            mnr[fr][rg] = BIG;
        }
    mpc[0] = mpc[1] = -BIG;
    mnc[0] = mnc[1] = BIG;

#pragma unroll
    for (int fr = 0; fr < 2; ++fr)
#pragma unroll
        for (int fc = 0; fc < 2; ++fc)
#pragma unroll
            for (int rg = 0; rg < 4; ++rg) {
                const int iLoc = wr * 32 + fr * 16 + (lane >> 4) * 4 + rg;
                const int jLoc = wc * 32 + fc * 16 + (lane & 15);
                const int i = rowBase + iLoc;
                const int j = colBase + jLoc;
                const float d2 = sqR[iLoc] + sqC[jLoc] - 2.f * acc[fr][fc][rg];
                const float d = sqrtf(fmaxf(d2, 1e-12f));
                const bool eq = (labR[iLoc] == labC[jLoc]);
                const float pv = (eq && (i != j)) ? d : -BIG;
                const float nv = eq ? BIG : d;
                mpr[fr][rg] = fmaxf(mpr[fr][rg], pv);
                mnr[fr][rg] = fminf(mnr[fr][rg], nv);
                mpc[fc] = fmaxf(mpc[fc], pv);
                mnc[fc] = fminf(mnc[fc], nv);
            }

#pragma unroll
    for (int mask = 1; mask < 16; mask <<= 1)
#pragma unroll
        for (int fr = 0; fr < 2; ++fr)
#pragma unroll
            for (int rg = 0; rg < 4; ++rg) {
                mpr[fr][rg] = fmaxf(mpr[fr][rg], __shfl_xor(mpr[fr][rg], mask));
                mnr[fr][rg] = fminf(mnr[fr][rg], __shfl_xor(mnr[fr][rg], mask));
            }
#pragma unroll
    for (int mask = 16; mask < 64; mask <<= 1)
#pragma unroll
        for (int fc = 0; fc < 2; ++fc) {
            mpc[fc] = fmaxf(mpc[fc], __shfl_xor(mpc[fc], mask));
            mnc[fc] = fminf(mnc[fc], __shfl_xor(mnc[fc], mask));
        }

    if ((lane & 15) == 0) {
#pragma unroll
        for (int fr = 0; fr < 2; ++fr)
#pragma unroll
            for (int rg = 0; rg < 4; ++rg) {
                const int i = rowBase + wr * 32 + fr * 16 + (lane >> 4) * 4 + rg;
                int fb = 0;
                if (mpr[fr][rg] > -1e37f) {
                    atomicMax(&hp[i], __float_as_int(mpr[fr][rg]));
                    fb |= 1;
                }
                if (mnr[fr][rg] < 1e37f) {
                    atomicMin(&hn[i], __float_as_int(mnr[fr][rg]));
                    fb |= 2;
                }
                if (fb) atomicOr(&flags[i], fb);
            }
    }
    if (lane < 16) {
#pragma unroll
        for (int fc = 0; fc < 2; ++fc) {
            const int j = colBase + wc * 32 + fc * 16 + lane;
            int fb = 0;
            if (mpc[fc] > -1e37f) {
                atomicMax(&hp[j], __float_as_int(mpc[fc]));
                fb |= 1;
            }
            if (mnc[fc] < 1e37f) {
                atomicMin(&hn[j], __float_as_int(mnc[fc]));
                fb |= 2;
            }
            if (fb) atomicOr(&flags[j], fb);
        }
    }
}

// ---------------- fallback path: fp32 vector (round-0 kernel) ----------------

#define BM 64
#define BN 64
#define BK 32

__global__ __launch_bounds__(256) void dist_f32_kernel(
    const float* __restrict__ F, const int* __restrict__ labels,
    const float* __restrict__ sq, int* __restrict__ hp, int* __restrict__ hn,
    int* __restrict__ flags) {
    __shared__ float As[BK][BM];
    __shared__ float Bs[BK][BN];
    __shared__ int labR[BM], labC[BN];
    __shared__ float sqR[BM], sqC[BN];

    const int rowBase = blockIdx.y * BM;
    const int colBase = blockIdx.x * BN;
    const int t = threadIdx.x;
    const int tx = t & 15;
    const int ty = t >> 4;

    if (t < 64) {
        labR[t] = labels[rowBase + t];
        sqR[t] = sq[rowBase + t];
    } else if (t < 128) {
        int u = t - 64;
        labC[u] = labels[colBase + u];
        sqC[u] = sq[colBase + u];
    }

    float acc[4][4] = {{0.f}};
    const int m = t & 63;
    const int q = t >> 6;
    const float* aRow = F + (size_t)(rowBase + m) * D_SZ + q * 8;
    const float* bRow = F + (size_t)(colBase + m) * D_SZ + q * 8;

    for (int k0 = 0; k0 < D_SZ; k0 += BK) {
        float4 a0 = *(const float4*)(aRow + k0);
        float4 a1 = *(const float4*)(aRow + k0 + 4);
        float4 b0 = *(const float4*)(bRow + k0);
        float4 b1 = *(const float4*)(bRow + k0 + 4);
        __syncthreads();
        int kb = q * 8;
        As[kb + 0][m] = a0.x; As[kb + 1][m] = a0.y;
        As[kb + 2][m] = a0.z; As[kb + 3][m] = a0.w;
        As[kb + 4][m] = a1.x; As[kb + 5][m] = a1.y;
        As[kb + 6][m] = a1.z; As[kb + 7][m] = a1.w;
        Bs[kb + 0][m] = b0.x; Bs[kb + 1][m] = b0.y;
        Bs[kb + 2][m] = b0.z; Bs[kb + 3][m] = b0.w;
        Bs[kb + 4][m] = b1.x; Bs[kb + 5][m] = b1.y;
        Bs[kb + 6][m] = b1.z; Bs[kb + 7][m] = b1.w;
        __syncthreads();
#pragma unroll
        for (int kk = 0; kk < BK; ++kk) {
            float4 a = *(const float4*)&As[kk][ty * 4];
            float4 b = *(const float4*)&Bs[kk][tx * 4];
            acc[0][0] += a.x * b.x; acc[0][1] += a.x * b.y;
            acc[0][2] += a.x * b.z; acc[0][3] += a.x * b.w;
            acc[1][0] += a.y * b.x; acc[1][1] += a.y * b.y;
            acc[1][2] += a.y * b.z; acc[1][3] += a.y * b.w;
            acc[2][0] += a.z * b.x; acc[2][1] += a.z * b.y;
            acc[2][2] += a.z * b.z; acc[2][3] += a.z * b.w;
            acc[3][0] += a.w * b.x; acc[3][1] += a.w * b.y;
            acc[3][2] += a.w * b.z; acc[3][3] += a.w * b.w;
        }
    }

    float mp[4], mn[4];
    int pf[4];
#pragma unroll
    for (int rr = 0; rr < 4; ++rr) {
        const int i = rowBase + ty * 4 + rr;
        const int li = labR[ty * 4 + rr];
        const float si = sqR[ty * 4 + rr];
        mp[rr] = -3.4e38f;
        mn[rr] = 3.4e38f;
        pf[rr] = 0;
#pragma unroll
        for (int c = 0; c < 4; ++c) {
            const int j = colBase + tx * 4 + c;
            const float d2 = si + sqC[tx * 4 + c] - 2.f * acc[rr][c];
            const float dist = sqrtf(fmaxf(d2, 1e-12f));
            const bool eq = (li == labC[tx * 4 + c]);
            if (eq && (i != j)) {
                mp[rr] = fmaxf(mp[rr], dist);
                pf[rr] |= 1;
            }
            if (!eq) {
                mn[rr] = fminf(mn[rr], dist);
                pf[rr] |= 2;
            }
        }
    }
#pragma unroll
    for (int mask = 1; mask < 16; mask <<= 1)
#pragma unroll
        for (int rr = 0; rr < 4; ++rr) {
            mp[rr] = fmaxf(mp[rr], __shfl_xor(mp[rr], mask));
            mn[rr] = fminf(mn[rr], __shfl_xor(mn[rr], mask));
            pf[rr] |= __shfl_xor(pf[rr], mask);
        }
    if (tx == 0) {
#pragma unroll
        for (int rr = 0; rr < 4; ++rr) {
            const int i = rowBase + ty * 4 + rr;
            if (pf[rr] & 1) atomicMax(&hp[i], __float_as_int(mp[rr]));
            if (pf[rr] & 2) atomicMin(&hn[i], __float_as_int(mn[rr]));
            if (pf[rr]) atomicOr(&flags[i], pf[rr]);
        }
    }
}

// ---------------- launch ----------------

extern "C" void kernel_launch(void* const* d_in, const int* in_sizes, int n_in,
                              void* d_out, int out_size, void* d_ws, size_t ws_size,
                              hipStream_t stream) {
    const float* F = (const float*)d_in[0];
    const int* labels = (const int*)d_in[1];
    float* out = (float*)d_out;
    char* ws = (char*)d_ws;

    const size_t FHLO = (size_t)B_SZ * D_SZ * 2;  // bytes per bf16 array (4 MB)
    const size_t need = 2 * FHLO + 16 * 1024;

    if (ws_size >= need) {
        unsigned short* Fhi = (unsigned short*)ws;
        unsigned short* Flo = (unsigned short*)(ws + FHLO);
        char* tail = ws + 2 * FHLO;
        float* sq = (float*)tail;
        int* hp = (int*)(tail + 4096);
        int* hn = (int*)(tail + 8192);
        int* flags = (int*)(tail + 12288);

        prep_kernel<<<(B_SZ * D_SZ) / (256 * 8), 256, 0, stream>>>(F, Fhi, Flo);
        sq_kernel<<<B_SZ, 256, 0, stream>>>(F, sq);
        init_kernel<<<B_SZ / 256, 256, 0, stream>>>(hp, hn, flags);
        dist_mfma_kernel<<<136, 256, 0, stream>>>(Fhi, Flo, labels, sq, hp, hn, flags);
        final_kernel<<<1, 1024, 0, stream>>>(hp, hn, flags, out);
    } else {
        float* sq = (float*)ws;
        int* hp = (int*)(ws + 4096);
        int* hn = (int*)(ws + 8192);
        int* flags = (int*)(ws + 12288);

        sq_kernel<<<B_SZ, 256, 0, stream>>>(F, sq);
        init_kernel<<<B_SZ / 256, 256, 0, stream>>>(hp, hn, flags);
        dim3 grid(B_SZ / BN, B_SZ / BM);
        dist_f32_kernel<<<grid, 256, 0, stream>>>(F, labels, sq, hp, hn, flags);
        final_kernel<<<1, 1024, 0, stream>>>(hp, hn, flags, out);
    }
}

// Round 3
// 33.201 us; speedup vs baseline: 3.6211x; 1.5924x over previous
//
#include <hip/hip_runtime.h>
#include <math.h>

#define B_SZ 1024
#define D_SZ 2048
#define MARGIN 0.3f

typedef _Float16 f16x8 __attribute__((ext_vector_type(8)));
typedef float f32x16 __attribute__((ext_vector_type(16)));

union H8 { _Float16 h[8]; uint4 u; };

// ---------------- small kernels ----------------

__global__ __launch_bounds__(256) void sq_kernel(const float* __restrict__ F,
                                                 float* __restrict__ sq) {
    int row = blockIdx.x;
    const float4* r4 = (const float4*)(F + (size_t)row * D_SZ);
    int t = threadIdx.x;
    float s = 0.f;
#pragma unroll
    for (int q = 0; q < 2; ++q) {
        float4 v = r4[t + q * 256];
        s += v.x * v.x + v.y * v.y + v.z * v.z + v.w * v.w;
    }
    for (int off = 32; off; off >>= 1) s += __shfl_down(s, off);
    __shared__ float wsum[4];
    if ((t & 63) == 0) wsum[t >> 6] = s;
    __syncthreads();
    if (t == 0) sq[row] = wsum[0] + wsum[1] + wsum[2] + wsum[3];
}

__global__ __launch_bounds__(256) void init_kernel(int* __restrict__ hp,
                                                   int* __restrict__ hn,
                                                   int* __restrict__ flags) {
    int i = blockIdx.x * 256 + threadIdx.x;
    hp[i] = 0;            // 0.0f bits; real dists are > 0
    hn[i] = 0x7F800000;   // +inf
    flags[i] = 0;
}

__global__ __launch_bounds__(1024) void final_kernel(const int* __restrict__ hp,
                                                     const int* __restrict__ hn,
                                                     const int* __restrict__ flags,
                                                     float* __restrict__ out) {
    __shared__ float ssum[16];
    __shared__ int svalid[16], sact[16];
    const int t = threadIdx.x;
    const float hpv = __int_as_float(hp[t]);
    const float hnv = __int_as_float(hn[t]);
    const int f = flags[t];
    const bool valid = (f == 3);
    float pr = fmaxf(hpv - hnv + MARGIN, 0.f);
    if (!valid) pr = 0.f;
    int act = (valid && pr > 0.f) ? 1 : 0;
    int vld = valid ? 1 : 0;
    float s = pr;
    for (int off = 32; off; off >>= 1) {
        s += __shfl_down(s, off);
        act += __shfl_down(act, off);
        vld += __shfl_down(vld, off);
    }
    if ((t & 63) == 0) {
        ssum[t >> 6] = s;
        svalid[t >> 6] = vld;
        sact[t >> 6] = act;
    }
    __syncthreads();
    if (t == 0) {
        float tot = 0.f;
        int nv = 0, na = 0;
#pragma unroll
        for (int i = 0; i < 16; ++i) {
            tot += ssum[i];
            nv += svalid[i];
            na += sact[i];
        }
        out[0] = tot / (float)(nv > 1 ? nv : 1);
        out[1] = (float)na;
    }
}

// ---------------- fast path: fp16 MFMA, pre-swizzled fragment-order ----------------
//
// Fh layout (16B granules): granule g = ((i*128 + kb16)*2 + rg)*64 + lane
//   holds F[i*64 + rg*32 + (lane&31)][kb16*16 + (lane>>5)*8 .. +8] as 8 fp16.
// This is exactly the v_mfma_f32_32x32x16_f16 A/B fragment order, so staging
// loads, global_load_lds (linear dest) and ds_read_b128 are all contiguous.

__global__ __launch_bounds__(256) void prep_f16_kernel(const float* __restrict__ F,
                                                       _Float16* __restrict__ Fh) {
    const int gid = blockIdx.x * 256 + threadIdx.x;   // 0 .. 256K-1 granules
    const int lane = gid & 63;
    const int rg = (gid >> 6) & 1;
    const int kb16 = (gid >> 7) & 127;
    const int i = gid >> 14;
    const int row = i * 64 + rg * 32 + (lane & 31);
    const int k = kb16 * 16 + (lane >> 5) * 8;
    const float4* s = (const float4*)(F + (size_t)row * D_SZ + k);
    const float4 x0 = s[0];
    const float4 x1 = s[1];
    H8 p;
    p.h[0] = (_Float16)x0.x; p.h[1] = (_Float16)x0.y;
    p.h[2] = (_Float16)x0.z; p.h[3] = (_Float16)x0.w;
    p.h[4] = (_Float16)x1.x; p.h[5] = (_Float16)x1.y;
    p.h[6] = (_Float16)x1.z; p.h[7] = (_Float16)x1.w;
    *(uint4*)(Fh + (size_t)gid * 8) = p.u;
}

#define WAVE_STAGE (3 * 8192)   // 3 ring buffers x 8KB (A 4KB + B 4KB)

__global__ __launch_bounds__(256) void dist_f16_kernel(
    const _Float16* __restrict__ Fh, const int* __restrict__ labels,
    const float* __restrict__ sq, int* __restrict__ hp, int* __restrict__ hn,
    int* __restrict__ flags) {
    __shared__ __align__(16) char stage[4 * WAVE_STAGE];   // 96KB, reused for combine
    __shared__ int labR[64], labC[64];
    __shared__ float sqR[64], sqC[64];

    const int t = threadIdx.x;
    const int lane = t & 63;
    const int w = t >> 6;   // wave id = K-quarter

    // XCD-friendly bijective swizzle: each XCD gets 2 contiguous tile-rows.
    const int tileId = (blockIdx.x & 7) * 32 + (blockIdx.x >> 3);
    const int bi = tileId >> 4;
    const int bj = tileId & 15;
    const int rowBase = bi * 64, colBase = bj * 64;

    if (t < 64) {
        labR[t] = labels[rowBase + t];
        sqR[t] = sq[rowBase + t];
    } else if (t < 128) {
        int u = t - 64;
        labC[u] = labels[colBase + u];
        sqC[u] = sq[colBase + u];
    }
    asm volatile("s_waitcnt vmcnt(0)" ::: "memory");   // clean vmcnt before counted loop

    const char* FhB = (const char*)Fh;
    char* wbase = stage + w * WAVE_STAGE;          // wave-uniform
    const char* rbase = wbase + lane * 16;         // per-lane read base

    f32x16 acc[2][2];
#pragma unroll
    for (int a = 0; a < 2; ++a)
#pragma unroll
        for (int c = 0; c < 2; ++c)
#pragma unroll
            for (int e = 0; e < 16; ++e) acc[a][c][e] = 0.f;

    // Issue one K=32 sub-step (8 x global_load_lds of 1KB, all contiguous).
    auto ISSUE = [&](int s, int b) {
        const int kb16 = w * 32 + s * 2;
        const size_t aOff = (size_t)((bi * 128 + kb16) * 2) * 1024 + (size_t)lane * 16;
        const size_t bOff = (size_t)((bj * 128 + kb16) * 2) * 1024 + (size_t)lane * 16;
        char* dA = wbase + b * 8192;
#pragma unroll
        for (int c = 0; c < 4; ++c)
            __builtin_amdgcn_global_load_lds(
                (const __attribute__((address_space(1))) void*)(FhB + aOff + c * 1024),
                (__attribute__((address_space(3))) void*)(dA + c * 1024), 16, 0, 0);
#pragma unroll
        for (int c = 0; c < 4; ++c)
            __builtin_amdgcn_global_load_lds(
                (const __attribute__((address_space(1))) void*)(FhB + bOff + c * 1024),
                (__attribute__((address_space(3))) void*)(dA + 4096 + c * 1024), 16, 0, 0);
    };
    // Consume one staged K=32 sub-step: 8 ds_read_b128 + 8 MFMA.
    auto COMPUTE = [&](int b) {
        const char* rb = rbase + b * 8192;
#pragma unroll
        for (int kl = 0; kl < 2; ++kl) {
            f16x8 a0 = *(const f16x8*)(rb + (kl * 2 + 0) * 1024);
            f16x8 a1 = *(const f16x8*)(rb + (kl * 2 + 1) * 1024);
            f16x8 v0 = *(const f16x8*)(rb + 4096 + (kl * 2 + 0) * 1024);
            f16x8 v1 = *(const f16x8*)(rb + 4096 + (kl * 2 + 1) * 1024);
            acc[0][0] = __builtin_amdgcn_mfma_f32_32x32x16_f16(a0, v0, acc[0][0], 0, 0, 0);
            acc[0][1] = __builtin_amdgcn_mfma_f32_32x32x16_f16(a0, v1, acc[0][1], 0, 0, 0);
            acc[1][0] = __builtin_amdgcn_mfma_f32_32x32x16_f16(a1, v0, acc[1][0], 0, 0, 0);
            acc[1][1] = __builtin_amdgcn_mfma_f32_32x32x16_f16(a1, v1, acc[1][1], 0, 0, 0);
        }
    };

#define WAIT16 asm volatile("s_waitcnt vmcnt(16)" ::: "memory"); __builtin_amdgcn_sched_barrier(0)
#define WAIT8  asm volatile("s_waitcnt vmcnt(8)"  ::: "memory"); __builtin_amdgcn_sched_barrier(0)
#define WAIT0  asm volatile("s_waitcnt vmcnt(0)"  ::: "memory"); __builtin_amdgcn_sched_barrier(0)

    ISSUE(0, 0);
    ISSUE(1, 1);
    for (int s3 = 0; s3 < 12; s3 += 3) {   // s = 0..11
        ISSUE(s3 + 2, 2); WAIT16; COMPUTE(0);
        ISSUE(s3 + 3, 0); WAIT16; COMPUTE(1);
        ISSUE(s3 + 4, 1); WAIT16; COMPUTE(2);
    }
    ISSUE(14, 2); WAIT16; COMPUTE(0);      // s = 12
    ISSUE(15, 0); WAIT16; COMPUTE(1);      // s = 13
    WAIT8;  COMPUTE(2);                    // s = 14
    WAIT0;  COMPUTE(0);                    // s = 15

    __syncthreads();

    // Combine the 4 K-partials through LDS (reuse staging area, 64KB).
    char* cb = stage;
#pragma unroll
    for (int fr = 0; fr < 2; ++fr)
#pragma unroll
        for (int fc = 0; fc < 2; ++fc)
#pragma unroll
            for (int g = 0; g < 4; ++g) {
                float4 v;
                v.x = acc[fr][fc][g * 4 + 0];
                v.y = acc[fr][fc][g * 4 + 1];
                v.z = acc[fr][fc][g * 4 + 2];
                v.w = acc[fr][fc][g * 4 + 3];
                *(float4*)(cb + ((size_t)((w * 16 + (fr * 2 + fc) * 4 + g) * 64 + lane)) * 16) = v;
            }
    __syncthreads();

    // Wave w owns frag (fr,fc) = (w>>1, w&1): sum 4 partials, then epilogue.
    const int fr = w >> 1, fc = w & 1;
    float cS[16];
#pragma unroll
    for (int e = 0; e < 16; ++e) cS[e] = 0.f;
#pragma unroll
    for (int wp = 0; wp < 4; ++wp)
#pragma unroll
        for (int g = 0; g < 4; ++g) {
            float4 v = *(const float4*)(cb + ((size_t)((wp * 16 + w * 4 + g) * 64 + lane)) * 16);
            cS[g * 4 + 0] += v.x;
            cS[g * 4 + 1] += v.y;
            cS[g * 4 + 2] += v.z;
            cS[g * 4 + 3] += v.w;
        }

    const float BIG = 1e38f;
    const int h = lane >> 5;
    const int colL = fc * 32 + (lane & 31);
    const int j = colBase + colL;
    const int lj = labC[colL];
    const float sqj = sqC[colL];
#pragma unroll
    for (int k = 0; k < 16; ++k) {
        const int rowL = fr * 32 + (k & 3) + 8 * (k >> 2) + 4 * h;
        const int i = rowBase + rowL;
        const float d2 = sqR[rowL] + sqj - 2.f * cS[k];
        const float d = sqrtf(fmaxf(d2, 1e-12f));
        const bool eq = (labR[rowL] == lj);
        const bool isPos = eq && (i != j);
        float pv = isPos ? d : -BIG;
        float nv = eq ? BIG : d;
        int pf = (isPos ? 1 : 0) | (eq ? 0 : 2);
#pragma unroll
        for (int mask = 1; mask < 32; mask <<= 1) {
            pv = fmaxf(pv, __shfl_xor(pv, mask));
            nv = fminf(nv, __shfl_xor(nv, mask));
            pf |= __shfl_xor(pf, mask);
        }
        if ((lane & 31) == 0) {
            if (pf & 1) atomicMax(&hp[i], __float_as_int(pv));
            if (pf & 2) atomicMin(&hn[i], __float_as_int(nv));
            if (pf) atomicOr(&flags[i], pf);
        }
    }
}

// ---------------- fallback path: fp32 vector (round-0 kernel) ----------------

#define BM 64
#define BN 64
#define BK 32

__global__ __launch_bounds__(256) void dist_f32_kernel(
    const float* __restrict__ F, const int* __restrict__ labels,
    const float* __restrict__ sq, int* __restrict__ hp, int* __restrict__ hn,
    int* __restrict__ flags) {
    __shared__ float As[BK][BM];
    __shared__ float Bs[BK][BN];
    __shared__ int labR[BM], labC[BN];
    __shared__ float sqR[BM], sqC[BN];

    const int rowBase = blockIdx.y * BM;
    const int colBase = blockIdx.x * BN;
    const int t = threadIdx.x;
    const int tx = t & 15;
    const int ty = t >> 4;

    if (t < 64) {
        labR[t] = labels[rowBase + t];
        sqR[t] = sq[rowBase + t];
    } else if (t < 128) {
        int u = t - 64;
        labC[u] = labels[colBase + u];
        sqC[u] = sq[colBase + u];
    }

    float acc[4][4] = {{0.f}};
    const int m = t & 63;
    const int q = t >> 6;
    const float* aRow = F + (size_t)(rowBase + m) * D_SZ + q * 8;
    const float* bRow = F + (size_t)(colBase + m) * D_SZ + q * 8;

    for (int k0 = 0; k0 < D_SZ; k0 += BK) {
        float4 a0 = *(const float4*)(aRow + k0);
        float4 a1 = *(const float4*)(aRow + k0 + 4);
        float4 b0 = *(const float4*)(bRow + k0);
        float4 b1 = *(const float4*)(bRow + k0 + 4);
        __syncthreads();
        int kb = q * 8;
        As[kb + 0][m] = a0.x; As[kb + 1][m] = a0.y;
        As[kb + 2][m] = a0.z; As[kb + 3][m] = a0.w;
        As[kb + 4][m] = a1.x; As[kb + 5][m] = a1.y;
        As[kb + 6][m] = a1.z; As[kb + 7][m] = a1.w;
        Bs[kb + 0][m] = b0.x; Bs[kb + 1][m] = b0.y;
        Bs[kb + 2][m] = b0.z; Bs[kb + 3][m] = b0.w;
        Bs[kb + 4][m] = b1.x; Bs[kb + 5][m] = b1.y;
        Bs[kb + 6][m] = b1.z; Bs[kb + 7][m] = b1.w;
        __syncthreads();
#pragma unroll
        for (int kk = 0; kk < BK; ++kk) {
            float4 a = *(const float4*)&As[kk][ty * 4];
            float4 b = *(const float4*)&Bs[kk][tx * 4];
            acc[0][0] += a.x * b.x; acc[0][1] += a.x * b.y;
            acc[0][2] += a.x * b.z; acc[0][3] += a.x * b.w;
            acc[1][0] += a.y * b.x; acc[1][1] += a.y * b.y;
            acc[1][2] += a.y * b.z; acc[1][3] += a.y * b.w;
            acc[2][0] += a.z * b.x; acc[2][1] += a.z * b.y;
            acc[2][2] += a.z * b.z; acc[2][3] += a.z * b.w;
            acc[3][0] += a.w * b.x; acc[3][1] += a.w * b.y;
            acc[3][2] += a.w * b.z; acc[3][3] += a.w * b.w;
        }
    }

    float mp[4], mn[4];
    int pf[4];
#pragma unroll
    for (int rr = 0; rr < 4; ++rr) {
        const int i = rowBase + ty * 4 + rr;
        const int li = labR[ty * 4 + rr];
        const float si = sqR[ty * 4 + rr];
        mp[rr] = -3.4e38f;
        mn[rr] = 3.4e38f;
        pf[rr] = 0;
#pragma unroll
        for (int c = 0; c < 4; ++c) {
            const int j = colBase + tx * 4 + c;
            const float d2 = si + sqC[tx * 4 + c] - 2.f * acc[rr][c];
            const float dist = sqrtf(fmaxf(d2, 1e-12f));
            const bool eq = (li == labC[tx * 4 + c]);
            if (eq && (i != j)) {
                mp[rr] = fmaxf(mp[rr], dist);
                pf[rr] |= 1;
            }
            if (!eq) {
                mn[rr] = fminf(mn[rr], dist);
                pf[rr] |= 2;
            }
        }
    }
#pragma unroll
    for (int mask = 1; mask < 16; mask <<= 1)
#pragma unroll
        for (int rr = 0; rr < 4; ++rr) {
            mp[rr] = fmaxf(mp[rr], __shfl_xor(mp[rr], mask));
            mn[rr] = fminf(mn[rr], __shfl_xor(mn[rr], mask));
            pf[rr] |= __shfl_xor(pf[rr], mask);
        }
    if (tx == 0) {
#pragma unroll
        for (int rr = 0; rr < 4; ++rr) {
            const int i = rowBase + ty * 4 + rr;
            if (pf[rr] & 1) atomicMax(&hp[i], __float_as_int(mp[rr]));
            if (pf[rr] & 2) atomicMin(&hn[i], __float_as_int(mn[rr]));
            if (pf[rr]) atomicOr(&flags[i], pf[rr]);
        }
    }
}

// ---------------- launch ----------------

extern "C" void kernel_launch(void* const* d_in, const int* in_sizes, int n_in,
                              void* d_out, int out_size, void* d_ws, size_t ws_size,
                              hipStream_t stream) {
    const float* F = (const float*)d_in[0];
    const int* labels = (const int*)d_in[1];
    float* out = (float*)d_out;
    char* ws = (char*)d_ws;

    const size_t FH = (size_t)B_SZ * D_SZ * 2;   // 4MB fp16 swizzled
    const size_t need = FH + 16 * 1024;

    if (ws_size >= need) {
        _Float16* Fh = (_Float16*)ws;
        char* tail = ws + FH;
        float* sq = (float*)tail;
        int* hp = (int*)(tail + 4096);
        int* hn = (int*)(tail + 8192);
        int* flags = (int*)(tail + 12288);

        prep_f16_kernel<<<(B_SZ * D_SZ) / (256 * 8), 256, 0, stream>>>(F, Fh);
        sq_kernel<<<B_SZ, 256, 0, stream>>>(F, sq);
        init_kernel<<<B_SZ / 256, 256, 0, stream>>>(hp, hn, flags);
        dist_f16_kernel<<<256, 256, 0, stream>>>(Fh, labels, sq, hp, hn, flags);
        final_kernel<<<1, 1024, 0, stream>>>(hp, hn, flags, out);
    } else {
        float* sq = (float*)ws;
        int* hp = (int*)(ws + 4096);
        int* hn = (int*)(ws + 8192);
        int* flags = (int*)(ws + 12288);

        sq_kernel<<<B_SZ, 256, 0, stream>>>(F, sq);
        init_kernel<<<B_SZ / 256, 256, 0, stream>>>(hp, hn, flags);
        dim3 grid(B_SZ / BN, B_SZ / BM);
        dist_f32_kernel<<<grid, 256, 0, stream>>>(F, labels, sq, hp, hn, flags);
        final_kernel<<<1, 1024, 0, stream>>>(hp, hn, flags, out);
    }
}